// Round 1
// baseline (835.831 us; speedup 1.0000x reference)
//
#include <hip/hip_runtime.h>

#define NN 100000
#define NE 1600000
#define DD 128
#define NB 98  // ceil(NN/1024)

// ---------------- preprocessing ----------------

__global__ __launch_bounds__(64) void k_detect(const unsigned int* __restrict__ w,
                                               int* __restrict__ flag) {
  if (blockIdx.x == 0 && threadIdx.x == 0) {
    int zeros = 0;
    for (int i = 1; i < 512; i += 2)
      if (w[i] == 0u) zeros++;
    *flag = (zeros >= 250) ? 1 : 0;  // int64 edge data has all-zero high words
  }
}

__global__ __launch_bounds__(256) void k_convert(const void* __restrict__ ei,
                                                 const int* __restrict__ flag,
                                                 int* __restrict__ ec) {
  int i = blockIdx.x * 256 + threadIdx.x;
  if (i < 2 * NE) {
    if (*flag)
      ec[i] = (int)((const long long*)ei)[i];
    else
      ec[i] = ((const int*)ei)[i];
  }
}

__global__ __launch_bounds__(256) void k_init(int* __restrict__ cnt) {
  int i = blockIdx.x * 256 + threadIdx.x;
  if (i < NN) cnt[i] = 0;
}

__global__ __launch_bounds__(256) void k_hist(const int* __restrict__ ec,
                                              int* __restrict__ cnt) {
  int e = blockIdx.x * 256 + threadIdx.x;
  if (e < NE) atomicAdd(&cnt[ec[NE + e]], 1);
}

__global__ __launch_bounds__(256) void k_dinv(const int* __restrict__ cnt,
                                              float* __restrict__ dinv) {
  int i = blockIdx.x * 256 + threadIdx.x;
  if (i < NN) dinv[i] = rsqrtf((float)(cnt[i] + 1));  // +1 self-loop; deg>=1 always
}

__global__ __launch_bounds__(256) void k_scan1(const int* __restrict__ cnt,
                                               int* __restrict__ bsums) {
  __shared__ int sd[256];
  const int tid = threadIdx.x;
  const int base = blockIdx.x * 1024;
  int s = 0;
#pragma unroll
  for (int j = 0; j < 4; j++) {
    int i = base + tid * 4 + j;
    if (i < NN) s += cnt[i];
  }
  sd[tid] = s;
  __syncthreads();
  for (int d = 128; d > 0; d >>= 1) {
    if (tid < d) sd[tid] += sd[tid + d];
    __syncthreads();
  }
  if (tid == 0) bsums[blockIdx.x] = sd[0];
}

__global__ void k_scan2(int* __restrict__ bsums, int* __restrict__ offs) {
  if (blockIdx.x == 0 && threadIdx.x == 0) {
    int run = 0;
    for (int b = 0; b < NB; b++) {
      int t = bsums[b];
      bsums[b] = run;
      run += t;
    }
    offs[NN] = run;  // == NE
  }
}

__global__ __launch_bounds__(256) void k_scan3(const int* __restrict__ cnt,
                                               const int* __restrict__ bsums,
                                               int* __restrict__ offs,
                                               int* __restrict__ cursor) {
  __shared__ int sd[256];
  const int tid = threadIdx.x;
  const int base = blockIdx.x * 1024;
  int v[4];
  int s = 0;
#pragma unroll
  for (int j = 0; j < 4; j++) {
    int i = base + tid * 4 + j;
    v[j] = (i < NN) ? cnt[i] : 0;
    s += v[j];
  }
  sd[tid] = s;
  __syncthreads();
  for (int d = 1; d < 256; d <<= 1) {
    int t = (tid >= d) ? sd[tid - d] : 0;
    __syncthreads();
    if (tid >= d) sd[tid] += t;
    __syncthreads();
  }
  int run = bsums[blockIdx.x] + sd[tid] - s;  // block offset + exclusive thread offset
#pragma unroll
  for (int j = 0; j < 4; j++) {
    int i = base + tid * 4 + j;
    if (i < NN) {
      offs[i] = run;
      cursor[i] = run;
    }
    run += v[j];
  }
}

__global__ __launch_bounds__(256) void k_fill(const int* __restrict__ ec,
                                              int* __restrict__ cursor,
                                              int* __restrict__ csr) {
  int e = blockIdx.x * 256 + threadIdx.x;
  if (e < NE) {
    int d = ec[NE + e];
    int pos = atomicAdd(&cursor[d], 1);
    csr[pos] = ec[e];  // src, grouped by dst
  }
}

// ---------------- per-layer kernels ----------------

// T[r][:] = (A[r][:] @ W) * dinv[r]
__global__ __launch_bounds__(256) void k_gemm(const float* __restrict__ A,
                                              const float* __restrict__ W,
                                              const float* __restrict__ dinv,
                                              float* __restrict__ T) {
  __shared__ float As[64][36];   // [row][k-chunk], pad 36 for alignment + banks
  __shared__ float Ws[32][128];  // [k][col]
  const int tid = threadIdx.x;
  const int row0 = blockIdx.x * 64;
  const int tr = tid >> 4;  // 0..15 -> 4 rows each
  const int tc = tid & 15;  // 0..15 -> 8 cols each
  float acc[4][8] = {};

  const int arow = tid >> 2;       // 0..63
  const int ak0 = (tid & 3) * 8;   // 0,8,16,24
  const int wk = tid >> 3;         // 0..31
  const int wc = (tid & 7) * 16;   // 0..112

  for (int kk = 0; kk < DD; kk += 32) {
    float4 a0, a1;
    int gr = row0 + arow;
    if (gr < NN) {
      const float* ap = A + (size_t)gr * DD + kk + ak0;
      a0 = *(const float4*)ap;
      a1 = *(const float4*)(ap + 4);
    } else {
      a0 = make_float4(0.f, 0.f, 0.f, 0.f);
      a1 = a0;
    }
    *(float4*)&As[arow][ak0] = a0;
    *(float4*)&As[arow][ak0 + 4] = a1;
    const float* wp = W + (size_t)(kk + wk) * DD + wc;
    *(float4*)&Ws[wk][wc] = *(const float4*)wp;
    *(float4*)&Ws[wk][wc + 4] = *(const float4*)(wp + 4);
    *(float4*)&Ws[wk][wc + 8] = *(const float4*)(wp + 8);
    *(float4*)&Ws[wk][wc + 12] = *(const float4*)(wp + 12);
    __syncthreads();
#pragma unroll
    for (int k = 0; k < 32; k++) {
      float av[4];
#pragma unroll
      for (int i = 0; i < 4; i++) av[i] = As[tr * 4 + i][k];
      float4 w0 = *(const float4*)&Ws[k][tc * 8];
      float4 w1 = *(const float4*)&Ws[k][tc * 8 + 4];
#pragma unroll
      for (int i = 0; i < 4; i++) {
        acc[i][0] += av[i] * w0.x;
        acc[i][1] += av[i] * w0.y;
        acc[i][2] += av[i] * w0.z;
        acc[i][3] += av[i] * w0.w;
        acc[i][4] += av[i] * w1.x;
        acc[i][5] += av[i] * w1.y;
        acc[i][6] += av[i] * w1.z;
        acc[i][7] += av[i] * w1.w;
      }
    }
    __syncthreads();
  }
#pragma unroll
  for (int i = 0; i < 4; i++) {
    int r = row0 + tr * 4 + i;
    if (r < NN) {
      float s = dinv[r];
      float4 o0 = make_float4(acc[i][0] * s, acc[i][1] * s, acc[i][2] * s, acc[i][3] * s);
      float4 o1 = make_float4(acc[i][4] * s, acc[i][5] * s, acc[i][6] * s, acc[i][7] * s);
      float* tp = T + (size_t)r * DD + tc * 8;
      *(float4*)tp = o0;
      *(float4*)(tp + 4) = o1;
    }
  }
}

// out[i] = relu(dinv[i] * (T[i] + sum_{e in CSR[i]} T[src_e]) + b)
// one wave per node, float2 per lane (64 lanes * 8B = 512B row)
__global__ __launch_bounds__(256) void k_agg(const float* __restrict__ T,
                                             const int* __restrict__ offs,
                                             const int* __restrict__ csr,
                                             const float* __restrict__ dinv,
                                             const float* __restrict__ bias,
                                             float* __restrict__ out) {
  const int lane = threadIdx.x & 63;
  const int node = blockIdx.x * 4 + (threadIdx.x >> 6);
  if (node >= NN) return;
  const float2* tp = (const float2*)T;  // row stride 64 float2
  float2 acc = tp[(size_t)node * 64 + lane];  // self-loop term
  int j = offs[node];
  const int end = offs[node + 1];
  for (; j + 4 <= end; j += 4) {
    int i0 = csr[j], i1 = csr[j + 1], i2 = csr[j + 2], i3 = csr[j + 3];
    float2 v0 = tp[(size_t)i0 * 64 + lane];
    float2 v1 = tp[(size_t)i1 * 64 + lane];
    float2 v2 = tp[(size_t)i2 * 64 + lane];
    float2 v3 = tp[(size_t)i3 * 64 + lane];
    acc.x += v0.x + v1.x + v2.x + v3.x;
    acc.y += v0.y + v1.y + v2.y + v3.y;
  }
  for (; j < end; ++j) {
    int i0 = csr[j];
    float2 v = tp[(size_t)i0 * 64 + lane];
    acc.x += v.x;
    acc.y += v.y;
  }
  float s = dinv[node];
  float2 bb = ((const float2*)bias)[lane];
  float ox = fmaxf(acc.x * s + bb.x, 0.f);
  float oy = fmaxf(acc.y * s + bb.y, 0.f);
  ((float2*)out)[(size_t)node * 64 + lane] = make_float2(ox, oy);
}

// ---------------- launch ----------------

extern "C" void kernel_launch(void* const* d_in, const int* in_sizes, int n_in,
                              void* d_out, int out_size, void* d_ws, size_t ws_size,
                              hipStream_t stream) {
  const float* x = (const float*)d_in[0];
  const void* ei = (const void*)d_in[1];
  const float* W1 = (const float*)d_in[2];
  const float* b1 = (const float*)d_in[3];
  const float* W2 = (const float*)d_in[4];
  const float* b2 = (const float*)d_in[5];
  const float* W3 = (const float*)d_in[6];
  const float* b3 = (const float*)d_in[7];
  float* out = (float*)d_out;

  char* p = (char*)d_ws;
  auto take = [&](size_t bytes) {
    char* r = p;
    p += (bytes + 1023) & ~(size_t)1023;
    return r;
  };
  int* flag = (int*)take(4);
  int* cnt = (int*)take((size_t)NN * 4);
  int* offs = (int*)take((size_t)(NN + 1) * 4);
  int* cursor = (int*)take((size_t)NN * 4);
  int* bsums = (int*)take((size_t)NB * 4);
  float* dinv = (float*)take((size_t)NN * 4);
  int* ec = (int*)take((size_t)2 * NE * 4);
  int* csr = (int*)take((size_t)NE * 4);
  float* tbuf = (float*)take((size_t)NN * DD * 4);
  float* hbuf = (float*)take((size_t)NN * DD * 4);

  const int nb_n = (NN + 255) / 256;
  const int nb_e = (NE + 255) / 256;
  const int nb_2e = (2 * NE + 255) / 256;

  k_detect<<<1, 64, 0, stream>>>((const unsigned int*)ei, flag);
  k_convert<<<nb_2e, 256, 0, stream>>>(ei, flag, ec);
  k_init<<<nb_n, 256, 0, stream>>>(cnt);
  k_hist<<<nb_e, 256, 0, stream>>>(ec, cnt);
  k_dinv<<<nb_n, 256, 0, stream>>>(cnt, dinv);
  k_scan1<<<NB, 256, 0, stream>>>(cnt, bsums);
  k_scan2<<<1, 64, 0, stream>>>(bsums, offs);
  k_scan3<<<NB, 256, 0, stream>>>(cnt, bsums, offs, cursor);
  k_fill<<<nb_e, 256, 0, stream>>>(ec, cursor, csr);

  const int gb = (NN + 63) / 64;
  const int ab = (NN + 3) / 4;
  k_gemm<<<gb, 256, 0, stream>>>(x, W1, dinv, tbuf);
  k_agg<<<ab, 256, 0, stream>>>(tbuf, offs, csr, dinv, b1, hbuf);
  k_gemm<<<gb, 256, 0, stream>>>(hbuf, W2, dinv, tbuf);
  k_agg<<<ab, 256, 0, stream>>>(tbuf, offs, csr, dinv, b2, hbuf);
  k_gemm<<<gb, 256, 0, stream>>>(hbuf, W3, dinv, tbuf);
  k_agg<<<ab, 256, 0, stream>>>(tbuf, offs, csr, dinv, b3, out);
}

// Round 2
// 789.605 us; speedup vs baseline: 1.0585x; 1.0585x over previous
//
#include <hip/hip_runtime.h>

#define NN 100000
#define NE 1600000
#define DD 128
#define NB 98        // ceil(NN/1024) for the scan
#define NGRP 8       // dst-space partitions (XCD count)
#define GBLK 128     // blocks per group for hist/fill
#define CHUNK (NE / GBLK)       // 12500 edges per block
#define CHUNK4 (CHUNK / 4)      // 3125 int4 per block
#define NPG (NN / NGRP)         // 12500 nodes per group

// ---------------- preprocessing ----------------

__global__ __launch_bounds__(64) void k_detect(const unsigned int* __restrict__ w,
                                               int* __restrict__ flag) {
  if (blockIdx.x == 0 && threadIdx.x == 0) {
    int zeros = 0;
    for (int i = 1; i < 512; i += 2)
      if (w[i] == 0u) zeros++;
    *flag = (zeros >= 250) ? 1 : 0;  // int64 edge data has all-zero high words
  }
}

__global__ __launch_bounds__(256) void k_convert(const void* __restrict__ ei,
                                                 const int* __restrict__ flag,
                                                 int* __restrict__ ec) {
  int i = blockIdx.x * 256 + threadIdx.x;
  if (i < 2 * NE) {
    if (*flag)
      ec[i] = (int)((const long long*)ei)[i];
    else
      ec[i] = ((const int*)ei)[i];
  }
}

__global__ __launch_bounds__(256) void k_init(int* __restrict__ cnt) {
  int i = blockIdx.x * 256 + threadIdx.x;
  if (i < NN) cnt[i] = 0;
}

// dst-partitioned histogram: group g = blockIdx&7 (XCD round-robin) only
// counts dst in its 12500-node range -> atomics stay XCD-local.
__global__ __launch_bounds__(256) void k_hist(const int* __restrict__ ec,
                                              int* __restrict__ cnt) {
  const int g = blockIdx.x & (NGRP - 1);
  const int bslot = blockIdx.x >> 3;
  const int lo = g * NPG, hi = lo + NPG;
  const int4* dst4 = (const int4*)(ec + NE + (size_t)bslot * CHUNK);
  for (int v = threadIdx.x; v < CHUNK4; v += 256) {
    int4 d = dst4[v];
    if (d.x >= lo && d.x < hi) atomicAdd(&cnt[d.x], 1);
    if (d.y >= lo && d.y < hi) atomicAdd(&cnt[d.y], 1);
    if (d.z >= lo && d.z < hi) atomicAdd(&cnt[d.z], 1);
    if (d.w >= lo && d.w < hi) atomicAdd(&cnt[d.w], 1);
  }
}

__global__ __launch_bounds__(256) void k_dinv(const int* __restrict__ cnt,
                                              float* __restrict__ dinv) {
  int i = blockIdx.x * 256 + threadIdx.x;
  if (i < NN) dinv[i] = rsqrtf((float)(cnt[i] + 1));  // +1 self-loop
}

__global__ __launch_bounds__(256) void k_scan1(const int* __restrict__ cnt,
                                               int* __restrict__ bsums) {
  __shared__ int sd[256];
  const int tid = threadIdx.x;
  const int base = blockIdx.x * 1024;
  int s = 0;
#pragma unroll
  for (int j = 0; j < 4; j++) {
    int i = base + tid * 4 + j;
    if (i < NN) s += cnt[i];
  }
  sd[tid] = s;
  __syncthreads();
  for (int d = 128; d > 0; d >>= 1) {
    if (tid < d) sd[tid] += sd[tid + d];
    __syncthreads();
  }
  if (tid == 0) bsums[blockIdx.x] = sd[0];
}

__global__ void k_scan2(int* __restrict__ bsums, int* __restrict__ offs) {
  if (blockIdx.x == 0 && threadIdx.x == 0) {
    int run = 0;
    for (int b = 0; b < NB; b++) {
      int t = bsums[b];
      bsums[b] = run;
      run += t;
    }
    offs[NN] = run;  // == NE
  }
}

__global__ __launch_bounds__(256) void k_scan3(const int* __restrict__ cnt,
                                               const int* __restrict__ bsums,
                                               int* __restrict__ offs,
                                               int* __restrict__ cursor) {
  __shared__ int sd[256];
  const int tid = threadIdx.x;
  const int base = blockIdx.x * 1024;
  int v[4];
  int s = 0;
#pragma unroll
  for (int j = 0; j < 4; j++) {
    int i = base + tid * 4 + j;
    v[j] = (i < NN) ? cnt[i] : 0;
    s += v[j];
  }
  sd[tid] = s;
  __syncthreads();
  for (int d = 1; d < 256; d <<= 1) {
    int t = (tid >= d) ? sd[tid - d] : 0;
    __syncthreads();
    if (tid >= d) sd[tid] += t;
    __syncthreads();
  }
  int run = bsums[blockIdx.x] + sd[tid] - s;
#pragma unroll
  for (int j = 0; j < 4; j++) {
    int i = base + tid * 4 + j;
    if (i < NN) {
      offs[i] = run;
      cursor[i] = run;
    }
    run += v[j];
  }
}

// dst-partitioned CSR fill: group g only scatters edges whose dst is in its
// range. That group's csr target region offs[lo]..offs[hi) is CONTIGUOUS and
// written by one XCD -> full 64B lines assemble in L2 (kills the 16x write
// amplification measured in R1: WRITE_SIZE 106MB for 6.4MB of payload).
__global__ __launch_bounds__(256) void k_fill(const int* __restrict__ ec,
                                              int* __restrict__ cursor,
                                              int* __restrict__ csr) {
  const int g = blockIdx.x & (NGRP - 1);
  const int bslot = blockIdx.x >> 3;
  const int lo = g * NPG, hi = lo + NPG;
  const int4* dst4 = (const int4*)(ec + NE + (size_t)bslot * CHUNK);
  const int4* src4 = (const int4*)(ec + (size_t)bslot * CHUNK);
  for (int v = threadIdx.x; v < CHUNK4; v += 256) {
    int4 d = dst4[v];
    int4 s = src4[v];
    if (d.x >= lo && d.x < hi) csr[atomicAdd(&cursor[d.x], 1)] = s.x;
    if (d.y >= lo && d.y < hi) csr[atomicAdd(&cursor[d.y], 1)] = s.y;
    if (d.z >= lo && d.z < hi) csr[atomicAdd(&cursor[d.z], 1)] = s.z;
    if (d.w >= lo && d.w < hi) csr[atomicAdd(&cursor[d.w], 1)] = s.w;
  }
}

// ---------------- per-layer kernels ----------------

// T[r][:] = (A[r][:] @ W) * dinv[r]
__global__ __launch_bounds__(256) void k_gemm(const float* __restrict__ A,
                                              const float* __restrict__ W,
                                              const float* __restrict__ dinv,
                                              float* __restrict__ T) {
  __shared__ float As[64][36];
  __shared__ float Ws[32][128];
  const int tid = threadIdx.x;
  const int row0 = blockIdx.x * 64;
  const int tr = tid >> 4;
  const int tc = tid & 15;
  float acc[4][8] = {};

  const int arow = tid >> 2;
  const int ak0 = (tid & 3) * 8;
  const int wk = tid >> 3;
  const int wc = (tid & 7) * 16;

  for (int kk = 0; kk < DD; kk += 32) {
    float4 a0, a1;
    int gr = row0 + arow;
    if (gr < NN) {
      const float* ap = A + (size_t)gr * DD + kk + ak0;
      a0 = *(const float4*)ap;
      a1 = *(const float4*)(ap + 4);
    } else {
      a0 = make_float4(0.f, 0.f, 0.f, 0.f);
      a1 = a0;
    }
    *(float4*)&As[arow][ak0] = a0;
    *(float4*)&As[arow][ak0 + 4] = a1;
    const float* wp = W + (size_t)(kk + wk) * DD + wc;
    *(float4*)&Ws[wk][wc] = *(const float4*)wp;
    *(float4*)&Ws[wk][wc + 4] = *(const float4*)(wp + 4);
    *(float4*)&Ws[wk][wc + 8] = *(const float4*)(wp + 8);
    *(float4*)&Ws[wk][wc + 12] = *(const float4*)(wp + 12);
    __syncthreads();
#pragma unroll
    for (int k = 0; k < 32; k++) {
      float av[4];
#pragma unroll
      for (int i = 0; i < 4; i++) av[i] = As[tr * 4 + i][k];
      float4 w0 = *(const float4*)&Ws[k][tc * 8];
      float4 w1 = *(const float4*)&Ws[k][tc * 8 + 4];
#pragma unroll
      for (int i = 0; i < 4; i++) {
        acc[i][0] += av[i] * w0.x;
        acc[i][1] += av[i] * w0.y;
        acc[i][2] += av[i] * w0.z;
        acc[i][3] += av[i] * w0.w;
        acc[i][4] += av[i] * w1.x;
        acc[i][5] += av[i] * w1.y;
        acc[i][6] += av[i] * w1.z;
        acc[i][7] += av[i] * w1.w;
      }
    }
    __syncthreads();
  }
#pragma unroll
  for (int i = 0; i < 4; i++) {
    int r = row0 + tr * 4 + i;
    if (r < NN) {
      float s = dinv[r];
      float4 o0 = make_float4(acc[i][0] * s, acc[i][1] * s, acc[i][2] * s, acc[i][3] * s);
      float4 o1 = make_float4(acc[i][4] * s, acc[i][5] * s, acc[i][6] * s, acc[i][7] * s);
      float* tp = T + (size_t)r * DD + tc * 8;
      *(float4*)tp = o0;
      *(float4*)(tp + 4) = o1;
    }
  }
}

// out[i] = relu(dinv[i] * (T[i] + sum_{e in CSR[i]} T[src_e]) + b)
// one wave per node, float2 per lane; 8-deep index unroll for MLP.
__global__ __launch_bounds__(256) void k_agg(const float* __restrict__ T,
                                             const int* __restrict__ offs,
                                             const int* __restrict__ csr,
                                             const float* __restrict__ dinv,
                                             const float* __restrict__ bias,
                                             float* __restrict__ out) {
  const int lane = threadIdx.x & 63;
  const int node = blockIdx.x * 4 + (threadIdx.x >> 6);
  if (node >= NN) return;
  const float2* tp = (const float2*)T;  // row stride 64 float2
  float2 acc = tp[(size_t)node * 64 + lane];  // self-loop term
  int j = offs[node];
  const int end = offs[node + 1];
  for (; j + 8 <= end; j += 8) {
    int i0 = csr[j], i1 = csr[j + 1], i2 = csr[j + 2], i3 = csr[j + 3];
    int i4 = csr[j + 4], i5 = csr[j + 5], i6 = csr[j + 6], i7 = csr[j + 7];
    float2 v0 = tp[(size_t)i0 * 64 + lane];
    float2 v1 = tp[(size_t)i1 * 64 + lane];
    float2 v2 = tp[(size_t)i2 * 64 + lane];
    float2 v3 = tp[(size_t)i3 * 64 + lane];
    float2 v4 = tp[(size_t)i4 * 64 + lane];
    float2 v5 = tp[(size_t)i5 * 64 + lane];
    float2 v6 = tp[(size_t)i6 * 64 + lane];
    float2 v7 = tp[(size_t)i7 * 64 + lane];
    acc.x += ((v0.x + v1.x) + (v2.x + v3.x)) + ((v4.x + v5.x) + (v6.x + v7.x));
    acc.y += ((v0.y + v1.y) + (v2.y + v3.y)) + ((v4.y + v5.y) + (v6.y + v7.y));
  }
  for (; j < end; ++j) {
    int i0 = csr[j];
    float2 v = tp[(size_t)i0 * 64 + lane];
    acc.x += v.x;
    acc.y += v.y;
  }
  float s = dinv[node];
  float2 bb = ((const float2*)bias)[lane];
  float ox = fmaxf(acc.x * s + bb.x, 0.f);
  float oy = fmaxf(acc.y * s + bb.y, 0.f);
  ((float2*)out)[(size_t)node * 64 + lane] = make_float2(ox, oy);
}

// ---------------- launch ----------------

extern "C" void kernel_launch(void* const* d_in, const int* in_sizes, int n_in,
                              void* d_out, int out_size, void* d_ws, size_t ws_size,
                              hipStream_t stream) {
  const float* x = (const float*)d_in[0];
  const void* ei = (const void*)d_in[1];
  const float* W1 = (const float*)d_in[2];
  const float* b1 = (const float*)d_in[3];
  const float* W2 = (const float*)d_in[4];
  const float* b2 = (const float*)d_in[5];
  const float* W3 = (const float*)d_in[6];
  const float* b3 = (const float*)d_in[7];
  float* out = (float*)d_out;

  char* p = (char*)d_ws;
  auto take = [&](size_t bytes) {
    char* r = p;
    p += (bytes + 1023) & ~(size_t)1023;
    return r;
  };
  int* flag = (int*)take(4);
  int* cnt = (int*)take((size_t)NN * 4);
  int* offs = (int*)take((size_t)(NN + 1) * 4);
  int* cursor = (int*)take((size_t)NN * 4);
  int* bsums = (int*)take((size_t)NB * 4);
  float* dinv = (float*)take((size_t)NN * 4);
  int* ec = (int*)take((size_t)2 * NE * 4);
  int* csr = (int*)take((size_t)NE * 4);
  float* tbuf = (float*)take((size_t)NN * DD * 4);
  float* hbuf = (float*)take((size_t)NN * DD * 4);

  const int nb_n = (NN + 255) / 256;
  const int nb_2e = (2 * NE + 255) / 256;

  k_detect<<<1, 64, 0, stream>>>((const unsigned int*)ei, flag);
  k_convert<<<nb_2e, 256, 0, stream>>>(ei, flag, ec);
  k_init<<<nb_n, 256, 0, stream>>>(cnt);
  k_hist<<<NGRP * GBLK, 256, 0, stream>>>(ec, cnt);
  k_dinv<<<nb_n, 256, 0, stream>>>(cnt, dinv);
  k_scan1<<<NB, 256, 0, stream>>>(cnt, bsums);
  k_scan2<<<1, 64, 0, stream>>>(bsums, offs);
  k_scan3<<<NB, 256, 0, stream>>>(cnt, bsums, offs, cursor);
  k_fill<<<NGRP * GBLK, 256, 0, stream>>>(ec, cursor, csr);

  const int gb = (NN + 63) / 64;
  const int ab = (NN + 3) / 4;
  k_gemm<<<gb, 256, 0, stream>>>(x, W1, dinv, tbuf);
  k_agg<<<ab, 256, 0, stream>>>(tbuf, offs, csr, dinv, b1, hbuf);
  k_gemm<<<gb, 256, 0, stream>>>(hbuf, W2, dinv, tbuf);
  k_agg<<<ab, 256, 0, stream>>>(tbuf, offs, csr, dinv, b2, hbuf);
  k_gemm<<<gb, 256, 0, stream>>>(hbuf, W3, dinv, tbuf);
  k_agg<<<ab, 256, 0, stream>>>(tbuf, offs, csr, dinv, b3, out);
}

// Round 3
// 648.081 us; speedup vs baseline: 1.2897x; 1.2184x over previous
//
#include <hip/hip_runtime.h>

#define NN 100000
#define NE 1600000
#define DD 128
#define NB 98        // ceil(NN/1024) for the scan
#define NGRP 8       // dst-space partitions (XCD count)
#define GBLK 128     // blocks per group for hist/fill
#define CHUNK (NE / GBLK)       // 12500 edges per block
#define CHUNK4 (CHUNK / 4)      // 3125 int4 per block
#define NPG (NN / NGRP)         // 12500 nodes per group

__device__ __forceinline__ unsigned bf16rn(float f) {
  unsigned u = __float_as_uint(f);
  return (u + 0x7fffu + ((u >> 16) & 1u)) >> 16;  // round-to-nearest-even
}
__device__ __forceinline__ unsigned pk2(float a, float b) {
  return bf16rn(a) | (bf16rn(b) << 16);
}
__device__ __forceinline__ float lo_f(unsigned u) { return __uint_as_float(u << 16); }
__device__ __forceinline__ float hi_f(unsigned u) { return __uint_as_float(u & 0xffff0000u); }

// ---------------- preprocessing ----------------

__global__ __launch_bounds__(64) void k_detect(const unsigned int* __restrict__ w,
                                               int* __restrict__ flag) {
  int lane = threadIdx.x;
  int z = 0;
  for (int i = lane; i < 256; i += 64)
    if (w[2 * i + 1] == 0u) z++;  // high words of first 256 int64s
  for (int d = 32; d > 0; d >>= 1) z += __shfl_down(z, d);
  if (lane == 0) *flag = (z >= 250) ? 1 : 0;
}

__global__ __launch_bounds__(256) void k_convert(const void* __restrict__ ei,
                                                 const int* __restrict__ flag,
                                                 int* __restrict__ ec) {
  int i = blockIdx.x * 256 + threadIdx.x;
  if (i < 2 * NE) {
    if (*flag)
      ec[i] = (int)((const long long*)ei)[i];
    else
      ec[i] = ((const int*)ei)[i];
  }
}

__global__ __launch_bounds__(256) void k_init(int* __restrict__ cnt) {
  int i = blockIdx.x * 256 + threadIdx.x;
  if (i < NN) cnt[i] = 0;
}

// dst-partitioned histogram: group g = blockIdx&7 (XCD round-robin) only
// counts dst in its 12500-node range -> atomics stay XCD-local.
__global__ __launch_bounds__(256) void k_hist(const int* __restrict__ ec,
                                              int* __restrict__ cnt) {
  const int g = blockIdx.x & (NGRP - 1);
  const int bslot = blockIdx.x >> 3;
  const int lo = g * NPG, hi = lo + NPG;
  const int4* dst4 = (const int4*)(ec + NE + (size_t)bslot * CHUNK);
  for (int v = threadIdx.x; v < CHUNK4; v += 256) {
    int4 d = dst4[v];
    if (d.x >= lo && d.x < hi) atomicAdd(&cnt[d.x], 1);
    if (d.y >= lo && d.y < hi) atomicAdd(&cnt[d.y], 1);
    if (d.z >= lo && d.z < hi) atomicAdd(&cnt[d.z], 1);
    if (d.w >= lo && d.w < hi) atomicAdd(&cnt[d.w], 1);
  }
}

__global__ __launch_bounds__(256) void k_dinv(const int* __restrict__ cnt,
                                              float* __restrict__ dinv) {
  int i = blockIdx.x * 256 + threadIdx.x;
  if (i < NN) dinv[i] = rsqrtf((float)(cnt[i] + 1));  // +1 self-loop
}

__global__ __launch_bounds__(256) void k_scan1(const int* __restrict__ cnt,
                                               int* __restrict__ bsums) {
  __shared__ int sd[256];
  const int tid = threadIdx.x;
  const int base = blockIdx.x * 1024;
  int s = 0;
#pragma unroll
  for (int j = 0; j < 4; j++) {
    int i = base + tid * 4 + j;
    if (i < NN) s += cnt[i];
  }
  sd[tid] = s;
  __syncthreads();
  for (int d = 128; d > 0; d >>= 1) {
    if (tid < d) sd[tid] += sd[tid + d];
    __syncthreads();
  }
  if (tid == 0) bsums[blockIdx.x] = sd[0];
}

// parallel 98-entry exclusive scan (was 1-thread serial: whole-GPU idle)
__global__ __launch_bounds__(128) void k_scan2(int* __restrict__ bsums,
                                               int* __restrict__ offs) {
  __shared__ int sd[128];
  const int tid = threadIdx.x;
  int v = (tid < NB) ? bsums[tid] : 0;
  sd[tid] = v;
  __syncthreads();
  for (int d = 1; d < 128; d <<= 1) {
    int t = (tid >= d) ? sd[tid - d] : 0;
    __syncthreads();
    sd[tid] += t;
    __syncthreads();
  }
  if (tid < NB) bsums[tid] = sd[tid] - v;  // exclusive
  if (tid == 127) offs[NN] = sd[127];      // == NE
}

__global__ __launch_bounds__(256) void k_scan3(const int* __restrict__ cnt,
                                               const int* __restrict__ bsums,
                                               int* __restrict__ offs,
                                               int* __restrict__ cursor) {
  __shared__ int sd[256];
  const int tid = threadIdx.x;
  const int base = blockIdx.x * 1024;
  int v[4];
  int s = 0;
#pragma unroll
  for (int j = 0; j < 4; j++) {
    int i = base + tid * 4 + j;
    v[j] = (i < NN) ? cnt[i] : 0;
    s += v[j];
  }
  sd[tid] = s;
  __syncthreads();
  for (int d = 1; d < 256; d <<= 1) {
    int t = (tid >= d) ? sd[tid - d] : 0;
    __syncthreads();
    if (tid >= d) sd[tid] += t;
    __syncthreads();
  }
  int run = bsums[blockIdx.x] + sd[tid] - s;
#pragma unroll
  for (int j = 0; j < 4; j++) {
    int i = base + tid * 4 + j;
    if (i < NN) {
      offs[i] = run;
      cursor[i] = run;
    }
    run += v[j];
  }
}

// dst-partitioned CSR fill (R1 fix: contiguous per-XCD target region)
__global__ __launch_bounds__(256) void k_fill(const int* __restrict__ ec,
                                              int* __restrict__ cursor,
                                              int* __restrict__ csr) {
  const int g = blockIdx.x & (NGRP - 1);
  const int bslot = blockIdx.x >> 3;
  const int lo = g * NPG, hi = lo + NPG;
  const int4* dst4 = (const int4*)(ec + NE + (size_t)bslot * CHUNK);
  const int4* src4 = (const int4*)(ec + (size_t)bslot * CHUNK);
  for (int v = threadIdx.x; v < CHUNK4; v += 256) {
    int4 d = dst4[v];
    int4 s = src4[v];
    if (d.x >= lo && d.x < hi) csr[atomicAdd(&cursor[d.x], 1)] = s.x;
    if (d.y >= lo && d.y < hi) csr[atomicAdd(&cursor[d.y], 1)] = s.y;
    if (d.z >= lo && d.z < hi) csr[atomicAdd(&cursor[d.z], 1)] = s.z;
    if (d.w >= lo && d.w < hi) csr[atomicAdd(&cursor[d.w], 1)] = s.w;
  }
}

// ---------------- per-layer kernels ----------------

// T[r][:] = bf16( (A[r][:] @ W) * dinv[r] )   -- 256B rows halve gather traffic
__global__ __launch_bounds__(256) void k_gemm(const float* __restrict__ A,
                                              const float* __restrict__ W,
                                              const float* __restrict__ dinv,
                                              unsigned* __restrict__ T) {
  __shared__ float As[64][36];
  __shared__ float Ws[32][128];
  const int tid = threadIdx.x;
  const int row0 = blockIdx.x * 64;
  const int tr = tid >> 4;
  const int tc = tid & 15;
  float acc[4][8] = {};

  const int arow = tid >> 2;
  const int ak0 = (tid & 3) * 8;
  const int wk = tid >> 3;
  const int wc = (tid & 7) * 16;

  for (int kk = 0; kk < DD; kk += 32) {
    float4 a0, a1;
    int gr = row0 + arow;
    if (gr < NN) {
      const float* ap = A + (size_t)gr * DD + kk + ak0;
      a0 = *(const float4*)ap;
      a1 = *(const float4*)(ap + 4);
    } else {
      a0 = make_float4(0.f, 0.f, 0.f, 0.f);
      a1 = a0;
    }
    *(float4*)&As[arow][ak0] = a0;
    *(float4*)&As[arow][ak0 + 4] = a1;
    const float* wp = W + (size_t)(kk + wk) * DD + wc;
    *(float4*)&Ws[wk][wc] = *(const float4*)wp;
    *(float4*)&Ws[wk][wc + 4] = *(const float4*)(wp + 4);
    *(float4*)&Ws[wk][wc + 8] = *(const float4*)(wp + 8);
    *(float4*)&Ws[wk][wc + 12] = *(const float4*)(wp + 12);
    __syncthreads();
#pragma unroll
    for (int k = 0; k < 32; k++) {
      float av[4];
#pragma unroll
      for (int i = 0; i < 4; i++) av[i] = As[tr * 4 + i][k];
      float4 w0 = *(const float4*)&Ws[k][tc * 8];
      float4 w1 = *(const float4*)&Ws[k][tc * 8 + 4];
#pragma unroll
      for (int i = 0; i < 4; i++) {
        acc[i][0] += av[i] * w0.x;
        acc[i][1] += av[i] * w0.y;
        acc[i][2] += av[i] * w0.z;
        acc[i][3] += av[i] * w0.w;
        acc[i][4] += av[i] * w1.x;
        acc[i][5] += av[i] * w1.y;
        acc[i][6] += av[i] * w1.z;
        acc[i][7] += av[i] * w1.w;
      }
    }
    __syncthreads();
  }
#pragma unroll
  for (int i = 0; i < 4; i++) {
    int r = row0 + tr * 4 + i;
    if (r < NN) {
      float s = dinv[r];
      uint4 o;
      o.x = pk2(acc[i][0] * s, acc[i][1] * s);
      o.y = pk2(acc[i][2] * s, acc[i][3] * s);
      o.z = pk2(acc[i][4] * s, acc[i][5] * s);
      o.w = pk2(acc[i][6] * s, acc[i][7] * s);
      *(uint4*)(T + (size_t)r * 64 + tc * 4) = o;
    }
  }
}

// out[i] = relu(dinv[i] * (T[i] + sum_{e in CSR[i]} T[src_e]) + b)
// one wave per node; bf16 rows: 1 uint (2 elems) per lane per row.
__global__ __launch_bounds__(256) void k_agg(const unsigned* __restrict__ T,
                                             const int* __restrict__ offs,
                                             const int* __restrict__ csr,
                                             const float* __restrict__ dinv,
                                             const float* __restrict__ bias,
                                             float* __restrict__ out) {
  const int lane = threadIdx.x & 63;
  const int node = blockIdx.x * 4 + (threadIdx.x >> 6);
  if (node >= NN) return;
  unsigned su = T[(size_t)node * 64 + lane];  // self-loop term
  float accx = lo_f(su), accy = hi_f(su);
  int j = offs[node];
  const int end = offs[node + 1];
  for (; j + 8 <= end; j += 8) {
    int i0 = csr[j], i1 = csr[j + 1], i2 = csr[j + 2], i3 = csr[j + 3];
    int i4 = csr[j + 4], i5 = csr[j + 5], i6 = csr[j + 6], i7 = csr[j + 7];
    unsigned u0 = T[(size_t)i0 * 64 + lane];
    unsigned u1 = T[(size_t)i1 * 64 + lane];
    unsigned u2 = T[(size_t)i2 * 64 + lane];
    unsigned u3 = T[(size_t)i3 * 64 + lane];
    unsigned u4 = T[(size_t)i4 * 64 + lane];
    unsigned u5 = T[(size_t)i5 * 64 + lane];
    unsigned u6 = T[(size_t)i6 * 64 + lane];
    unsigned u7 = T[(size_t)i7 * 64 + lane];
    accx += ((lo_f(u0) + lo_f(u1)) + (lo_f(u2) + lo_f(u3))) +
            ((lo_f(u4) + lo_f(u5)) + (lo_f(u6) + lo_f(u7)));
    accy += ((hi_f(u0) + hi_f(u1)) + (hi_f(u2) + hi_f(u3))) +
            ((hi_f(u4) + hi_f(u5)) + (hi_f(u6) + hi_f(u7)));
  }
  for (; j < end; ++j) {
    unsigned u = T[(size_t)csr[j] * 64 + lane];
    accx += lo_f(u);
    accy += hi_f(u);
  }
  float s = dinv[node];
  float2 bb = ((const float2*)bias)[lane];
  float ox = fmaxf(accx * s + bb.x, 0.f);
  float oy = fmaxf(accy * s + bb.y, 0.f);
  ((float2*)out)[(size_t)node * 64 + lane] = make_float2(ox, oy);
}

// ---------------- launch ----------------

extern "C" void kernel_launch(void* const* d_in, const int* in_sizes, int n_in,
                              void* d_out, int out_size, void* d_ws, size_t ws_size,
                              hipStream_t stream) {
  const float* x = (const float*)d_in[0];
  const void* ei = (const void*)d_in[1];
  const float* W1 = (const float*)d_in[2];
  const float* b1 = (const float*)d_in[3];
  const float* W2 = (const float*)d_in[4];
  const float* b2 = (const float*)d_in[5];
  const float* W3 = (const float*)d_in[6];
  const float* b3 = (const float*)d_in[7];
  float* out = (float*)d_out;

  char* p = (char*)d_ws;
  auto take = [&](size_t bytes) {
    char* r = p;
    p += (bytes + 1023) & ~(size_t)1023;
    return r;
  };
  int* flag = (int*)take(4);
  int* cnt = (int*)take((size_t)NN * 4);
  int* offs = (int*)take((size_t)(NN + 1) * 4);
  int* cursor = (int*)take((size_t)NN * 4);
  int* bsums = (int*)take((size_t)NB * 4);
  float* dinv = (float*)take((size_t)NN * 4);
  int* ec = (int*)take((size_t)2 * NE * 4);
  int* csr = (int*)take((size_t)NE * 4);
  unsigned* tbuf = (unsigned*)take((size_t)NN * 64 * 4);  // bf16 rows: 64 uints
  float* hbuf = (float*)take((size_t)NN * DD * 4);

  const int nb_n = (NN + 255) / 256;
  const int nb_2e = (2 * NE + 255) / 256;

  k_detect<<<1, 64, 0, stream>>>((const unsigned int*)ei, flag);
  k_convert<<<nb_2e, 256, 0, stream>>>(ei, flag, ec);
  k_init<<<nb_n, 256, 0, stream>>>(cnt);
  k_hist<<<NGRP * GBLK, 256, 0, stream>>>(ec, cnt);
  k_dinv<<<nb_n, 256, 0, stream>>>(cnt, dinv);
  k_scan1<<<NB, 256, 0, stream>>>(cnt, bsums);
  k_scan2<<<1, 128, 0, stream>>>(bsums, offs);
  k_scan3<<<NB, 256, 0, stream>>>(cnt, bsums, offs, cursor);
  k_fill<<<NGRP * GBLK, 256, 0, stream>>>(ec, cursor, csr);

  const int gb = (NN + 63) / 64;
  const int ab = (NN + 3) / 4;
  k_gemm<<<gb, 256, 0, stream>>>(x, W1, dinv, tbuf);
  k_agg<<<ab, 256, 0, stream>>>(tbuf, offs, csr, dinv, b1, hbuf);
  k_gemm<<<gb, 256, 0, stream>>>(hbuf, W2, dinv, tbuf);
  k_agg<<<ab, 256, 0, stream>>>(tbuf, offs, csr, dinv, b2, hbuf);
  k_gemm<<<gb, 256, 0, stream>>>(hbuf, W3, dinv, tbuf);
  k_agg<<<ab, 256, 0, stream>>>(tbuf, offs, csr, dinv, b3, out);
}

// Round 4
// 522.780 us; speedup vs baseline: 1.5988x; 1.2397x over previous
//
#include <hip/hip_runtime.h>

#define NN 100000
#define NE 1600000
#define DD 128
#define NB 98        // ceil(NN/1024) for the scan
#define NGRP 8       // dst-space partitions (XCD count)
#define GBLK 128     // blocks per group for hist/fill
#define CHUNK (NE / GBLK)       // 12500 edges per block
#define CHUNK4 (CHUNK / 4)      // 3125 int4 per block
#define NPG (NN / NGRP)         // 12500 nodes per group
#define CSRCAP 1900032          // >= NE + 3*NN (deg padded to multiple of 4)

typedef __attribute__((ext_vector_type(8))) short short8;
typedef __attribute__((ext_vector_type(4))) float f32x4;

__device__ __forceinline__ unsigned bf16rn(float f) {
  unsigned u = __float_as_uint(f);
  return (u + 0x7fffu + ((u >> 16) & 1u)) >> 16;  // round-to-nearest-even
}
__device__ __forceinline__ unsigned pk2(float a, float b) {
  return bf16rn(a) | (bf16rn(b) << 16);
}
__device__ __forceinline__ float lo_f(unsigned u) { return __uint_as_float(u << 16); }
__device__ __forceinline__ float hi_f(unsigned u) { return __uint_as_float(u & 0xffff0000u); }

// ---------------- preprocessing ----------------

__global__ __launch_bounds__(64) void k_detect(const unsigned int* __restrict__ w,
                                               int* __restrict__ flag) {
  int lane = threadIdx.x;
  int z = 0;
  for (int i = lane; i < 256; i += 64)
    if (w[2 * i + 1] == 0u) z++;  // high words of first 256 int64s
  for (int d = 32; d > 0; d >>= 1) z += __shfl_down(z, d);
  if (lane == 0) *flag = (z >= 250) ? 1 : 0;
}

__global__ __launch_bounds__(256) void k_convert(const void* __restrict__ ei,
                                                 const int* __restrict__ flag,
                                                 int* __restrict__ ec) {
  int i = blockIdx.x * 256 + threadIdx.x;
  if (i < 2 * NE) {
    if (*flag)
      ec[i] = (int)((const long long*)ei)[i];
    else
      ec[i] = ((const int*)ei)[i];
  }
}

// zero degree counts + prefill csr with the dummy zero-row index NN
__global__ __launch_bounds__(256) void k_init(int* __restrict__ cnt,
                                              int* __restrict__ csr) {
  int i = blockIdx.x * 256 + threadIdx.x;
  if (i < NN) cnt[i] = 0;
  if (i < CSRCAP) csr[i] = NN;
}

// dst-partitioned histogram (XCD-local atomics)
__global__ __launch_bounds__(256) void k_hist(const int* __restrict__ ec,
                                              int* __restrict__ cnt) {
  const int g = blockIdx.x & (NGRP - 1);
  const int bslot = blockIdx.x >> 3;
  const int lo = g * NPG, hi = lo + NPG;
  const int4* dst4 = (const int4*)(ec + NE + (size_t)bslot * CHUNK);
  for (int v = threadIdx.x; v < CHUNK4; v += 256) {
    int4 d = dst4[v];
    if (d.x >= lo && d.x < hi) atomicAdd(&cnt[d.x], 1);
    if (d.y >= lo && d.y < hi) atomicAdd(&cnt[d.y], 1);
    if (d.z >= lo && d.z < hi) atomicAdd(&cnt[d.z], 1);
    if (d.w >= lo && d.w < hi) atomicAdd(&cnt[d.w], 1);
  }
}

// dinv + zero the dummy T row (row NN)
__global__ __launch_bounds__(256) void k_dinv(const int* __restrict__ cnt,
                                              float* __restrict__ dinv,
                                              unsigned* __restrict__ tbuf) {
  int i = blockIdx.x * 256 + threadIdx.x;
  if (i < NN) dinv[i] = rsqrtf((float)(cnt[i] + 1));  // +1 self-loop
  if (blockIdx.x == 0 && threadIdx.x < 64) tbuf[(size_t)NN * 64 + threadIdx.x] = 0u;
}

// scans below use PADDED counts: pc = (cnt+3) & ~3  (int4-aligned segments)
__global__ __launch_bounds__(256) void k_scan1(const int* __restrict__ cnt,
                                               int* __restrict__ bsums) {
  __shared__ int sd[256];
  const int tid = threadIdx.x;
  const int base = blockIdx.x * 1024;
  int s = 0;
#pragma unroll
  for (int j = 0; j < 4; j++) {
    int i = base + tid * 4 + j;
    if (i < NN) s += (cnt[i] + 3) & ~3;
  }
  sd[tid] = s;
  __syncthreads();
  for (int d = 128; d > 0; d >>= 1) {
    if (tid < d) sd[tid] += sd[tid + d];
    __syncthreads();
  }
  if (tid == 0) bsums[blockIdx.x] = sd[0];
}

__global__ __launch_bounds__(128) void k_scan2(int* __restrict__ bsums,
                                               int* __restrict__ offs) {
  __shared__ int sd[128];
  const int tid = threadIdx.x;
  int v = (tid < NB) ? bsums[tid] : 0;
  sd[tid] = v;
  __syncthreads();
  for (int d = 1; d < 128; d <<= 1) {
    int t = (tid >= d) ? sd[tid - d] : 0;
    __syncthreads();
    sd[tid] += t;
    __syncthreads();
  }
  if (tid < NB) bsums[tid] = sd[tid] - v;  // exclusive
  if (tid == 127) offs[NN] = sd[127];      // padded total
}

__global__ __launch_bounds__(256) void k_scan3(const int* __restrict__ cnt,
                                               const int* __restrict__ bsums,
                                               int* __restrict__ offs,
                                               int* __restrict__ cursor) {
  __shared__ int sd[256];
  const int tid = threadIdx.x;
  const int base = blockIdx.x * 1024;
  int v[4];
  int s = 0;
#pragma unroll
  for (int j = 0; j < 4; j++) {
    int i = base + tid * 4 + j;
    v[j] = (i < NN) ? ((cnt[i] + 3) & ~3) : 0;
    s += v[j];
  }
  sd[tid] = s;
  __syncthreads();
  for (int d = 1; d < 256; d <<= 1) {
    int t = (tid >= d) ? sd[tid - d] : 0;
    __syncthreads();
    if (tid >= d) sd[tid] += t;
    __syncthreads();
  }
  int run = bsums[blockIdx.x] + sd[tid] - s;
#pragma unroll
  for (int j = 0; j < 4; j++) {
    int i = base + tid * 4 + j;
    if (i < NN) {
      offs[i] = run;
      cursor[i] = run;
    }
    run += v[j];
  }
}

// dst-partitioned CSR fill (contiguous per-XCD target region)
__global__ __launch_bounds__(256) void k_fill(const int* __restrict__ ec,
                                              int* __restrict__ cursor,
                                              int* __restrict__ csr) {
  const int g = blockIdx.x & (NGRP - 1);
  const int bslot = blockIdx.x >> 3;
  const int lo = g * NPG, hi = lo + NPG;
  const int4* dst4 = (const int4*)(ec + NE + (size_t)bslot * CHUNK);
  const int4* src4 = (const int4*)(ec + (size_t)bslot * CHUNK);
  for (int v = threadIdx.x; v < CHUNK4; v += 256) {
    int4 d = dst4[v];
    int4 s = src4[v];
    if (d.x >= lo && d.x < hi) csr[atomicAdd(&cursor[d.x], 1)] = s.x;
    if (d.y >= lo && d.y < hi) csr[atomicAdd(&cursor[d.y], 1)] = s.y;
    if (d.z >= lo && d.z < hi) csr[atomicAdd(&cursor[d.z], 1)] = s.z;
    if (d.w >= lo && d.w < hi) csr[atomicAdd(&cursor[d.w], 1)] = s.w;
  }
}

// Wt[n][k] = bf16(W[k][n]), packed 2 bf16 per uint (k pairs)
__global__ __launch_bounds__(256) void k_prepw(const float* __restrict__ W,
                                               unsigned* __restrict__ wt) {
  int id = blockIdx.x * 256 + threadIdx.x;  // 0..8191
  int n = id >> 6, kp = id & 63;
  wt[n * 64 + kp] = pk2(W[(size_t)(2 * kp) * DD + n], W[(size_t)(2 * kp + 1) * DD + n]);
}

// ---------------- MFMA GEMM:  T[r][:] = bf16( (A[r][:] @ W) * dinv[r] ) ----
// 64-row x 128-col tile, 4 waves (32 cols each), 16x16x32 bf16 MFMA.
// LDS: A-tile 16KB + Wt 32KB, both XOR-swizzled (byte ^= (row&7)<<4 per 16B seg).
template <bool F32SRC>
__global__ __launch_bounds__(256) void k_gemm(const void* __restrict__ Av,
                                              const unsigned* __restrict__ Wg,
                                              const float* __restrict__ dinv,
                                              unsigned* __restrict__ T) {
  __shared__ char lds[49408];  // 0:A(16K) 16384:Wt(32K) 49152:dinv(256B)
  const int t = threadIdx.x;
  const int row0 = blockIdx.x * 64;
  const int w = t >> 6, l = t & 63;
  const int lm = l & 15, kb = l >> 4;

  // stage A tile (64 rows x 128 bf16)
  {
    int r = t >> 2;
    int gr = row0 + r;
#pragma unroll
    for (int s4 = 0; s4 < 4; s4++) {
      int sg = (t & 3) * 4 + s4;  // 16B segment 0..15
      uint4 u;
      if (gr < NN) {
        if (F32SRC) {
          const float* ap = (const float*)Av + (size_t)gr * DD + sg * 8;
          float4 f0 = *(const float4*)ap;
          float4 f1 = *(const float4*)(ap + 4);
          u.x = pk2(f0.x, f0.y); u.y = pk2(f0.z, f0.w);
          u.z = pk2(f1.x, f1.y); u.w = pk2(f1.z, f1.w);
        } else {
          u = *(const uint4*)((const unsigned*)Av + (size_t)gr * 64 + sg * 4);
        }
      } else {
        u = make_uint4(0u, 0u, 0u, 0u);
      }
      *(uint4*)(lds + r * 256 + ((sg * 16) ^ ((r & 7) << 4))) = u;
    }
  }
  // stage Wt (128 rows x 128 bf16)
#pragma unroll
  for (int q = 0; q < 8; q++) {
    int e = t * 8 + q;  // 0..2047
    int n = e >> 4, sg = e & 15;
    uint4 u = *(const uint4*)(Wg + n * 64 + sg * 4);
    *(uint4*)(lds + 16384 + n * 256 + ((sg * 16) ^ ((n & 7) << 4))) = u;
  }
  // stage dinv
  if (t < 64) {
    int gr = row0 + t;
    *(float*)(lds + 49152 + t * 4) = (gr < NN) ? dinv[gr] : 0.f;
  }
  __syncthreads();

  f32x4 acc[4][2];
#pragma unroll
  for (int i = 0; i < 4; i++)
#pragma unroll
    for (int j = 0; j < 2; j++) acc[i][j] = (f32x4){0.f, 0.f, 0.f, 0.f};

#pragma unroll
  for (int kk = 0; kk < 4; kk++) {
    const int koff = (kk * 4 + kb) * 16;  // byte offset of this lane's 8 bf16
    short8 af[4], bf[2];
#pragma unroll
    for (int i = 0; i < 4; i++) {
      int r = i * 16 + lm;
      af[i] = *(const short8*)(lds + r * 256 + (koff ^ ((r & 7) << 4)));
    }
#pragma unroll
    for (int j = 0; j < 2; j++) {
      int n = w * 32 + j * 16 + lm;
      bf[j] = *(const short8*)(lds + 16384 + n * 256 + (koff ^ ((n & 7) << 4)));
    }
#pragma unroll
    for (int i = 0; i < 4; i++)
#pragma unroll
      for (int j = 0; j < 2; j++)
        acc[i][j] = __builtin_amdgcn_mfma_f32_16x16x32_bf16(af[i], bf[j], acc[i][j], 0, 0, 0);
  }

  // epilogue: scale by dinv[row], pack col-pairs via shfl, store uints
#pragma unroll
  for (int i = 0; i < 4; i++) {
#pragma unroll
    for (int j = 0; j < 2; j++) {
#pragma unroll
      for (int q = 0; q < 4; q++) {
        int rl = i * 16 + (l >> 4) * 4 + q;  // local row
        float s = *(const float*)(lds + 49152 + rl * 4);
        float v = acc[i][j][q] * s;
        float nb = __shfl_xor(v, 1);
        if ((l & 1) == 0) {
          int gr = row0 + rl;
          if (gr < NN) {
            int cp = w * 16 + j * 8 + (lm >> 1);
            T[(size_t)gr * 64 + cp] = pk2(v, nb);
          }
        }
      }
    }
  }
}

// ---------------- aggregation ----------------
// out[i] = relu(dinv[i] * (T[i] + sum_{e in CSR[i]} T[src_e]) + b)
// one wave per node; segments padded to x4 with dummy row NN (zeros).
template <bool BF16OUT>
__global__ __launch_bounds__(256) void k_agg(const unsigned* __restrict__ T,
                                             const int* __restrict__ offs,
                                             const int* __restrict__ csr,
                                             const float* __restrict__ dinv,
                                             const float* __restrict__ bias,
                                             void* __restrict__ outv) {
  const int lane = threadIdx.x & 63;
  const int node = blockIdx.x * 4 + (threadIdx.x >> 6);
  if (node >= NN) return;
  unsigned su = T[(size_t)node * 64 + lane];  // self-loop term
  float accx = lo_f(su), accy = hi_f(su);
  int j = offs[node];
  const int end = offs[node + 1];
  for (; j + 16 <= end; j += 16) {
    int4 c0 = *(const int4*)(csr + j);
    int4 c1 = *(const int4*)(csr + j + 4);
    int4 c2 = *(const int4*)(csr + j + 8);
    int4 c3 = *(const int4*)(csr + j + 12);
    unsigned u0 = T[(size_t)c0.x * 64 + lane];
    unsigned u1 = T[(size_t)c0.y * 64 + lane];
    unsigned u2 = T[(size_t)c0.z * 64 + lane];
    unsigned u3 = T[(size_t)c0.w * 64 + lane];
    unsigned u4 = T[(size_t)c1.x * 64 + lane];
    unsigned u5 = T[(size_t)c1.y * 64 + lane];
    unsigned u6 = T[(size_t)c1.z * 64 + lane];
    unsigned u7 = T[(size_t)c1.w * 64 + lane];
    unsigned u8 = T[(size_t)c2.x * 64 + lane];
    unsigned u9 = T[(size_t)c2.y * 64 + lane];
    unsigned ua = T[(size_t)c2.z * 64 + lane];
    unsigned ub = T[(size_t)c2.w * 64 + lane];
    unsigned uc = T[(size_t)c3.x * 64 + lane];
    unsigned ud = T[(size_t)c3.y * 64 + lane];
    unsigned ue = T[(size_t)c3.z * 64 + lane];
    unsigned uf = T[(size_t)c3.w * 64 + lane];
    accx += (((lo_f(u0) + lo_f(u1)) + (lo_f(u2) + lo_f(u3))) +
             ((lo_f(u4) + lo_f(u5)) + (lo_f(u6) + lo_f(u7)))) +
            (((lo_f(u8) + lo_f(u9)) + (lo_f(ua) + lo_f(ub))) +
             ((lo_f(uc) + lo_f(ud)) + (lo_f(ue) + lo_f(uf))));
    accy += (((hi_f(u0) + hi_f(u1)) + (hi_f(u2) + hi_f(u3))) +
             ((hi_f(u4) + hi_f(u5)) + (hi_f(u6) + hi_f(u7)))) +
            (((hi_f(u8) + hi_f(u9)) + (hi_f(ua) + hi_f(ub))) +
             ((hi_f(uc) + hi_f(ud)) + (hi_f(ue) + hi_f(uf))));
  }
  for (; j < end; j += 4) {
    int4 c = *(const int4*)(csr + j);
    unsigned u0 = T[(size_t)c.x * 64 + lane];
    unsigned u1 = T[(size_t)c.y * 64 + lane];
    unsigned u2 = T[(size_t)c.z * 64 + lane];
    unsigned u3 = T[(size_t)c.w * 64 + lane];
    accx += (lo_f(u0) + lo_f(u1)) + (lo_f(u2) + lo_f(u3));
    accy += (hi_f(u0) + hi_f(u1)) + (hi_f(u2) + hi_f(u3));
  }
  float s = dinv[node];
  float2 bb = ((const float2*)bias)[lane];
  float ox = fmaxf(accx * s + bb.x, 0.f);
  float oy = fmaxf(accy * s + bb.y, 0.f);
  if (BF16OUT)
    ((unsigned*)outv)[(size_t)node * 64 + lane] = pk2(ox, oy);
  else
    ((float2*)outv)[(size_t)node * 64 + lane] = make_float2(ox, oy);
}

// ---------------- launch ----------------

extern "C" void kernel_launch(void* const* d_in, const int* in_sizes, int n_in,
                              void* d_out, int out_size, void* d_ws, size_t ws_size,
                              hipStream_t stream) {
  const float* x = (const float*)d_in[0];
  const void* ei = (const void*)d_in[1];
  const float* W1 = (const float*)d_in[2];
  const float* b1 = (const float*)d_in[3];
  const float* W2 = (const float*)d_in[4];
  const float* b2 = (const float*)d_in[5];
  const float* W3 = (const float*)d_in[6];
  const float* b3 = (const float*)d_in[7];
  float* out = (float*)d_out;

  char* p = (char*)d_ws;
  auto take = [&](size_t bytes) {
    char* r = p;
    p += (bytes + 1023) & ~(size_t)1023;
    return r;
  };
  int* flag = (int*)take(4);
  int* cnt = (int*)take((size_t)NN * 4);
  int* offs = (int*)take((size_t)(NN + 1) * 4);
  int* cursor = (int*)take((size_t)NN * 4);
  int* bsums = (int*)take((size_t)NB * 4);
  float* dinv = (float*)take((size_t)NN * 4);
  int* ec = (int*)take((size_t)2 * NE * 4);
  int* csr = (int*)take((size_t)CSRCAP * 4);
  unsigned* tbuf = (unsigned*)take((size_t)(NN + 1) * 64 * 4);  // +1 dummy zero row
  unsigned* hbuf = (unsigned*)take((size_t)NN * 64 * 4);        // bf16 hidden
  unsigned* wt1 = (unsigned*)take((size_t)DD * 64 * 4);
  unsigned* wt2 = (unsigned*)take((size_t)DD * 64 * 4);
  unsigned* wt3 = (unsigned*)take((size_t)DD * 64 * 4);

  const int nb_2e = (2 * NE + 255) / 256;
  const int nb_cap = (CSRCAP + 255) / 256;
  const int nb_n = (NN + 255) / 256;

  k_detect<<<1, 64, 0, stream>>>((const unsigned int*)ei, flag);
  k_convert<<<nb_2e, 256, 0, stream>>>(ei, flag, ec);
  k_init<<<nb_cap, 256, 0, stream>>>(cnt, csr);
  k_hist<<<NGRP * GBLK, 256, 0, stream>>>(ec, cnt);
  k_dinv<<<nb_n, 256, 0, stream>>>(cnt, dinv, tbuf);
  k_scan1<<<NB, 256, 0, stream>>>(cnt, bsums);
  k_scan2<<<1, 128, 0, stream>>>(bsums, offs);
  k_scan3<<<NB, 256, 0, stream>>>(cnt, bsums, offs, cursor);
  k_fill<<<NGRP * GBLK, 256, 0, stream>>>(ec, cursor, csr);
  k_prepw<<<32, 256, 0, stream>>>(W1, wt1);
  k_prepw<<<32, 256, 0, stream>>>(W2, wt2);
  k_prepw<<<32, 256, 0, stream>>>(W3, wt3);

  const int gb = (NN + 63) / 64;
  const int ab = (NN + 3) / 4;
  k_gemm<true><<<gb, 256, 0, stream>>>(x, wt1, dinv, tbuf);
  k_agg<true><<<ab, 256, 0, stream>>>(tbuf, offs, csr, dinv, b1, hbuf);
  k_gemm<false><<<gb, 256, 0, stream>>>(hbuf, wt2, dinv, tbuf);
  k_agg<true><<<ab, 256, 0, stream>>>(tbuf, offs, csr, dinv, b2, hbuf);
  k_gemm<false><<<gb, 256, 0, stream>>>(hbuf, wt3, dinv, tbuf);
  k_agg<false><<<ab, 256, 0, stream>>>(tbuf, offs, csr, dinv, b3, out);
}